// Round 5
// baseline (192.716 us; speedup 1.0000x reference)
//
#include <hip/hip_runtime.h>

#define E_TOTAL 800000
#define NN      50000
#define ND      64
#define ED      32
#define HD      128
#define OD      64
#define IND     160      // ED + 2*ND
#define MT      128      // edges per tile
#define NTHREADS 512
#define NT      (E_TOTAL / MT)   // 6250 tiles
#define GRID    512              // persistent blocks, 2/CU

typedef __attribute__((ext_vector_type(8))) short          short8;
typedef __attribute__((ext_vector_type(4))) float          f32x4;
typedef __attribute__((ext_vector_type(8))) unsigned short u16x8;
typedef __attribute__((ext_vector_type(4))) unsigned short u16x4;

__device__ __forceinline__ unsigned short f2bf(float f) {
  union { float f; unsigned u; } v; v.f = f;
  unsigned r = v.u + 0x7fffu + ((v.u >> 16) & 1u);   // RNE
  return (unsigned short)(r >> 16);
}

// LDS: H (32 frags, wave-private: frags [wid*4, wid*4+4)) + W1 (40 frags).
// frag = 1024B, lane l's 16B at frag*1024 + l*16 -> conflict-free b128 ops.
#define H_FRAGS  32
#define SMEM_U16 ((H_FRAGS + 40) * 512)     // 36864 u16
#define SMEM_BYTES (SMEM_U16 * 2)           // 73728 B -> 2 blocks/CU

// ---------- prepass: f32 -> bf16 node table ----------
__global__ void cvt_nodes(const float* __restrict__ in, unsigned short* __restrict__ out, int n4) {
  int i = blockIdx.x * blockDim.x + threadIdx.x;
  const int stride = gridDim.x * blockDim.x;
  for (; i < n4; i += stride) {
    float4 v = ((const float4*)in)[i];
    u16x4 o = { f2bf(v.x), f2bf(v.y), f2bf(v.z), f2bf(v.w) };
    ((u16x4*)out)[i] = o;
  }
}

// ---------- prepass: pack W1 into B-fragment order ----------
__global__ void pack_w1(const float* __restrict__ w, unsigned short* __restrict__ out) {
  int i = blockIdx.x * blockDim.x + threadIdx.x;
  if (i >= HD * IND) return;
  int j = i & 7, l = (i >> 3) & 63, f = i >> 9;   // f in [0,40)
  int ks = f >> 3, t = f & 7;
  int k = ks * 32 + (l >> 4) * 8 + j;
  int n = t * 16 + (l & 15);
  out[i] = f2bf(w[k * HD + n]);
}

// ---------- prepass: pack W2 into B-fragment order ----------
__global__ void pack_w2(const float* __restrict__ w, unsigned short* __restrict__ out) {
  int i = blockIdx.x * blockDim.x + threadIdx.x;
  if (i >= OD * HD) return;
  int j = i & 7, l = (i >> 3) & 63, f = i >> 9;   // f in [0,16)
  int ks = f >> 2, t = f & 3;
  int k = ks * 32 + (l >> 4) * 8 + j;
  int n = t * 16 + (l & 15);
  out[i] = f2bf(w[k * OD + n]);
}

// ---------- main fused persistent kernel ----------
__global__ __launch_bounds__(NTHREADS, 4)
void edge_mlp(const int* __restrict__ eidx,
              const float* __restrict__ ef,
              const unsigned short* __restrict__ nbf,
              const unsigned short* __restrict__ w1p,
              const unsigned short* __restrict__ w2p,
              const float* __restrict__ b1,
              const float* __restrict__ b2,
              float* __restrict__ out)
{
  extern __shared__ unsigned short sm[];
  unsigned short* Hs = sm;                  // 32 frags, wave-private slices
  unsigned short* W1 = sm + H_FRAGS * 512;  // 40 frags (staged once)

  const int tid  = threadIdx.x;
  const int wid  = tid >> 6;
  const int lane = tid & 63;
  const int lq   = lane >> 4;
  const int lr   = lane & 15;
  const int rowoff = wid * 16 + lr;

  // ---- stage W1 once ----
  #pragma unroll
  for (int c = 0; c < 5; ++c) {
    const int i = tid + c * NTHREADS;
    *(u16x8*)(W1 + i * 8) = *(const u16x8*)(w1p + i * 8);
  }

  float b1v[8];
  #pragma unroll
  for (int t = 0; t < 8; ++t) b1v[t] = b1[t * 16 + lr];
  float b2v[4];
  #pragma unroll
  for (int t = 0; t < 4; ++t) b2v[t] = b2[t * 16 + lr];

  __syncthreads();   // W1 visible; the only draining barrier

  // ---- gather: node rows + edge features into a named register set ----
  #define GATHER(G0,G1,G2,G3,EV0,EV1, SI, TI, EOFF)                         \
    {                                                                        \
      int si_ = (SI); si_ = si_ < 0 ? 0 : (si_ >= NN ? NN - 1 : si_);        \
      int ti_ = (TI); ti_ = ti_ < 0 ? 0 : (ti_ >= NN ? NN - 1 : ti_);        \
      const unsigned short* sr_ = nbf + (long)si_ * ND;                      \
      const unsigned short* tr_ = nbf + (long)ti_ * ND;                      \
      G0 = *(const short8*)(sr_ + lq * 8);                                   \
      G1 = *(const short8*)(sr_ + 32 + lq * 8);                              \
      G2 = *(const short8*)(tr_ + lq * 8);                                   \
      G3 = *(const short8*)(tr_ + 32 + lq * 8);                              \
      EV0 = *(const float4*)(ef + (long)(EOFF) * ED + lq * 8);               \
      EV1 = *(const float4*)(ef + (long)(EOFF) * ED + lq * 8 + 4);           \
    }

  // ---- full tile compute from a register set ----
  #define COMPUTE(G0,G1,G2,G3,EV0,EV1, TILE)                                 \
    {                                                                        \
      short8 aef;                                                            \
      aef[0] = (short)f2bf(EV0.x); aef[1] = (short)f2bf(EV0.y);              \
      aef[2] = (short)f2bf(EV0.z); aef[3] = (short)f2bf(EV0.w);              \
      aef[4] = (short)f2bf(EV1.x); aef[5] = (short)f2bf(EV1.y);              \
      aef[6] = (short)f2bf(EV1.z); aef[7] = (short)f2bf(EV1.w);              \
      f32x4 acc[8];                                                          \
      _Pragma("unroll")                                                      \
      for (int t = 0; t < 8; ++t) acc[t] = (f32x4)0.0f;                      \
      _Pragma("unroll")                                                      \
      for (int t = 0; t < 8; ++t) {                                          \
        const short8 b = *(const short8*)(W1 + (1 * 8 + t) * 512 + lane * 8);\
        acc[t] = __builtin_amdgcn_mfma_f32_16x16x32_bf16(G0, b, acc[t], 0, 0, 0); } \
      _Pragma("unroll")                                                      \
      for (int t = 0; t < 8; ++t) {                                          \
        const short8 b = *(const short8*)(W1 + (2 * 8 + t) * 512 + lane * 8);\
        acc[t] = __builtin_amdgcn_mfma_f32_16x16x32_bf16(G1, b, acc[t], 0, 0, 0); } \
      _Pragma("unroll")                                                      \
      for (int t = 0; t < 8; ++t) {                                          \
        const short8 b = *(const short8*)(W1 + (3 * 8 + t) * 512 + lane * 8);\
        acc[t] = __builtin_amdgcn_mfma_f32_16x16x32_bf16(G2, b, acc[t], 0, 0, 0); } \
      _Pragma("unroll")                                                      \
      for (int t = 0; t < 8; ++t) {                                          \
        const short8 b = *(const short8*)(W1 + (4 * 8 + t) * 512 + lane * 8);\
        acc[t] = __builtin_amdgcn_mfma_f32_16x16x32_bf16(G3, b, acc[t], 0, 0, 0); } \
      _Pragma("unroll")                                                      \
      for (int t = 0; t < 8; ++t) {                                          \
        const short8 b = *(const short8*)(W1 + (0 * 8 + t) * 512 + lane * 8);\
        acc[t] = __builtin_amdgcn_mfma_f32_16x16x32_bf16(aef, b, acc[t], 0, 0, 0); } \
      _Pragma("unroll")                                                      \
      for (int t = 0; t < 8; ++t) {                                          \
        _Pragma("unroll")                                                    \
        for (int r = 0; r < 4; ++r) {                                        \
          float h = acc[t][r] + b1v[t];                                      \
          h = h > 0.0f ? h : 0.0f;                                           \
          const int k    = t * 16 + lr;                                      \
          const int frag = wid * 4 + (k >> 5);                               \
          const int l2   = (((k >> 3) & 3) << 4) + lq * 4 + r;               \
          Hs[frag * 512 + l2 * 8 + (k & 7)] = f2bf(h);                       \
        }                                                                    \
      }                                                                      \
      short8 a2[4];                                                          \
      _Pragma("unroll")                                                      \
      for (int ks = 0; ks < 4; ++ks)                                         \
        a2[ks] = *(const short8*)(Hs + (wid * 4 + ks) * 512 + lane * 8);     \
      f32x4 acc2[4];                                                         \
      _Pragma("unroll")                                                      \
      for (int t = 0; t < 4; ++t) acc2[t] = (f32x4)0.0f;                     \
      _Pragma("unroll")                                                      \
      for (int t = 0; t < 4; ++t) {                                          \
        _Pragma("unroll")                                                    \
        for (int ks = 0; ks < 4; ++ks) {                                     \
          const short8 b = *(const short8*)(w2p + ((ks * 4 + t) * 64 + lane) * 8); \
          acc2[t] = __builtin_amdgcn_mfma_f32_16x16x32_bf16(a2[ks], b, acc2[t], 0, 0, 0); } } \
      const long mbase = (long)(TILE) * MT + wid * 16 + lq * 4;              \
      _Pragma("unroll")                                                      \
      for (int t = 0; t < 4; ++t) {                                          \
        _Pragma("unroll")                                                    \
        for (int r = 0; r < 4; ++r) {                                        \
          out[(mbase + r) * OD + t * 16 + lr] = acc2[t][r] + b2v[t];         \
        }                                                                    \
      }                                                                      \
    }

  int tile = blockIdx.x;

  // ---- prologue: gathers for tile into set A; idx prefetch for tile+GRID
  short8 gA0, gA1, gA2, gA3;  float4 eA0, eA1;
  short8 gB0, gB1, gB2, gB3;  float4 eB0, eB1;
  {
    const int e = tile * MT + rowoff;
    GATHER(gA0, gA1, gA2, gA3, eA0, eA1, eidx[e], eidx[E_TOTAL + e], e);
  }
  int eoff1, sN1, tN1, eoff2, sN2, tN2;
  {
    int tn = tile + GRID; if (tn >= NT) tn = NT - 1;
    eoff1 = tn * MT + rowoff;
    sN1 = eidx[eoff1]; tN1 = eidx[E_TOTAL + eoff1];
  }

  // ---- main loop: 2 tiles per iteration, A/B register double-buffer
  for (; tile + GRID < NT; tile += 2 * GRID) {
    __builtin_amdgcn_s_barrier();           // pacing only (no data dep, no drain)
    GATHER(gB0, gB1, gB2, gB3, eB0, eB1, sN1, tN1, eoff1);
    {
      int tn = tile + 2 * GRID; if (tn >= NT) tn = NT - 1;
      eoff2 = tn * MT + rowoff;
      sN2 = eidx[eoff2]; tN2 = eidx[E_TOTAL + eoff2];
    }
    COMPUTE(gA0, gA1, gA2, gA3, eA0, eA1, tile);

    __builtin_amdgcn_s_barrier();           // pacing only
    GATHER(gA0, gA1, gA2, gA3, eA0, eA1, sN2, tN2, eoff2);
    {
      int tn = tile + 3 * GRID; if (tn >= NT) tn = NT - 1;
      eoff1 = tn * MT + rowoff;
      sN1 = eidx[eoff1]; tN1 = eidx[E_TOTAL + eoff1];
    }
    COMPUTE(gB0, gB1, gB2, gB3, eB0, eB1, tile + GRID);
  }
  // ---- tail (odd trip count): set A holds this tile's gathers
  if (tile < NT) {
    COMPUTE(gA0, gA1, gA2, gA3, eA0, eA1, tile);
  }

  #undef GATHER
  #undef COMPUTE
}

extern "C" void kernel_launch(void* const* d_in, const int* in_sizes, int n_in,
                              void* d_out, int out_size, void* d_ws, size_t ws_size,
                              hipStream_t stream) {
  const int*   eidx = (const int*)d_in[0];      // (2, E) int32
  const float* nf   = (const float*)d_in[1];    // (NN, 64)
  const float* ef   = (const float*)d_in[2];    // (E, 32)
  const float* w1   = (const float*)d_in[3];    // (160, 128)
  const float* b1   = (const float*)d_in[4];    // (128,)
  const float* w2   = (const float*)d_in[5];    // (128, 64)
  const float* b2   = (const float*)d_in[6];    // (64,)
  float*       out  = (float*)d_out;            // (E, 64)

  unsigned short* nbf = (unsigned short*)d_ws;            // NN*ND
  unsigned short* w1p = nbf + (long)NN * ND;              // HD*IND
  unsigned short* w2p = w1p + (long)HD * IND;             // OD*HD

  cvt_nodes<<<1024, 256, 0, stream>>>(nf, nbf, (NN * ND) / 4);
  pack_w1<<<(HD * IND + 255) / 256, 256, 0, stream>>>(w1, w1p);
  pack_w2<<<(OD * HD + 255) / 256, 256, 0, stream>>>(w2, w2p);

  hipFuncSetAttribute((const void*)edge_mlp,
                      hipFuncAttributeMaxDynamicSharedMemorySize, SMEM_BYTES);
  edge_mlp<<<GRID, NTHREADS, SMEM_BYTES, stream>>>(
      eidx, ef, nbf, w1p, w2p, b1, b2, out);
}

// Round 6
// 132.386 us; speedup vs baseline: 1.4557x; 1.4557x over previous
//
#include <hip/hip_runtime.h>

#define E_TOTAL 800000
#define NN      50000
#define ND      64
#define ED      32
#define HD      128
#define OD      64
#define IND     160      // ED + 2*ND
#define MT      128      // edges per block
#define NTHREADS 512

typedef __attribute__((ext_vector_type(8))) short          short8;
typedef __attribute__((ext_vector_type(4))) float          f32x4;
typedef __attribute__((ext_vector_type(8))) unsigned short u16x8;
typedef __attribute__((ext_vector_type(4))) unsigned short u16x4;

__device__ __forceinline__ unsigned short f2bf(float f) {
  union { float f; unsigned u; } v; v.f = f;
  unsigned r = v.u + 0x7fffu + ((v.u >> 16) & 1u);   // RNE
  return (unsigned short)(r >> 16);
}

// LDS: H (32 frags, wave-private: wave w owns frags [w*4, w*4+4)) + W1 (40 frags).
// frag = 1024B; lane l's 16B at frag*1024 + l*16 -> conflict-free b128 ops.
#define H_FRAGS  32
#define SMEM_U16 ((H_FRAGS + 40) * 512)     // 36864 u16
#define SMEM_BYTES (SMEM_U16 * 2)           // 73728 B -> 2 blocks/CU

// ---------- prepass: f32 -> bf16 node table ----------
__global__ void cvt_nodes(const float* __restrict__ in, unsigned short* __restrict__ out, int n4) {
  int i = blockIdx.x * blockDim.x + threadIdx.x;
  const int stride = gridDim.x * blockDim.x;
  for (; i < n4; i += stride) {
    float4 v = ((const float4*)in)[i];
    u16x4 o = { f2bf(v.x), f2bf(v.y), f2bf(v.z), f2bf(v.w) };
    ((u16x4*)out)[i] = o;
  }
}

// ---------- prepass: pack W1 into B-fragment order ----------
__global__ void pack_w1(const float* __restrict__ w, unsigned short* __restrict__ out) {
  int i = blockIdx.x * blockDim.x + threadIdx.x;
  if (i >= HD * IND) return;
  int j = i & 7, l = (i >> 3) & 63, f = i >> 9;   // f in [0,40)
  int ks = f >> 3, t = f & 7;
  int k = ks * 32 + (l >> 4) * 8 + j;
  int n = t * 16 + (l & 15);
  out[i] = f2bf(w[k * HD + n]);
}

// ---------- prepass: pack W2 into B-fragment order ----------
__global__ void pack_w2(const float* __restrict__ w, unsigned short* __restrict__ out) {
  int i = blockIdx.x * blockDim.x + threadIdx.x;
  if (i >= OD * HD) return;
  int j = i & 7, l = (i >> 3) & 63, f = i >> 9;   // f in [0,16)
  int ks = f >> 2, t = f & 3;
  int k = ks * 32 + (l >> 4) * 8 + j;
  int n = t * 16 + (l & 15);
  out[i] = f2bf(w[k * OD + n]);
}

// ---------- main fused kernel: one 128-edge tile per block ----------
__global__ __launch_bounds__(NTHREADS, 4)
void edge_mlp(const int* __restrict__ eidx,
              const float* __restrict__ ef,
              const unsigned short* __restrict__ nbf,
              const unsigned short* __restrict__ w1p,
              const unsigned short* __restrict__ w2p,
              const float* __restrict__ b1,
              const float* __restrict__ b2,
              float* __restrict__ out)
{
  extern __shared__ unsigned short sm[];
  unsigned short* Hs = sm;                  // 32 frags, wave-private slices
  unsigned short* W1 = sm + H_FRAGS * 512;  // 40 frags

  const int tid  = threadIdx.x;
  const int wid  = tid >> 6;
  const int lane = tid & 63;
  const int lq   = lane >> 4;
  const int lr   = lane & 15;
  const long e   = (long)blockIdx.x * MT + wid * 16 + lr;   // this lane's edge row

  // ---- 1) index loads first: head of the dependent chain
  int si = eidx[e];
  int ti = eidx[E_TOTAL + e];

  // ---- 2) edge features (independent, in flight early)
  const float4 e0v = *(const float4*)(ef + e * ED + lq * 8);
  const float4 e1v = *(const float4*)(ef + e * ED + lq * 8 + 4);

  // ---- 3) W1 chunk loads (independent, linear, coalesced)
  u16x8 wv[5];
  #pragma unroll
  for (int c = 0; c < 5; ++c)
    wv[c] = *(const u16x8*)(w1p + (tid + c * NTHREADS) * 8);

  // ---- 4) biases (L1-broadcast)
  float b1v[8];
  #pragma unroll
  for (int t = 0; t < 8; ++t) b1v[t] = b1[t * 16 + lr];
  float b2v[4];
  #pragma unroll
  for (int t = 0; t < 4; ++t) b2v[t] = b2[t * 16 + lr];

  // ---- 5) node-row gathers straight into this lane's A-frag registers
  si = si < 0 ? 0 : (si >= NN ? NN - 1 : si);
  ti = ti < 0 ? 0 : (ti >= NN ? NN - 1 : ti);
  const unsigned short* sr = nbf + (long)si * ND;
  const unsigned short* tr = nbf + (long)ti * ND;
  const short8 g0 = *(const short8*)(sr + lq * 8);
  const short8 g1 = *(const short8*)(sr + 32 + lq * 8);
  const short8 g2 = *(const short8*)(tr + lq * 8);
  const short8 g3 = *(const short8*)(tr + 32 + lq * 8);

  // ---- 6) W1 -> LDS (conflict-free b128; compiler waits only the wv vmcnt)
  #pragma unroll
  for (int c = 0; c < 5; ++c)
    *(u16x8*)(W1 + (tid + c * NTHREADS) * 8) = wv[c];

  // ---- 7) the ONLY barrier: W1 visible. lgkm-only wait — gathers stay in flight.
  asm volatile("s_waitcnt lgkmcnt(0)" ::: "memory");
  __builtin_amdgcn_s_barrier();

  // ---- A-frag ks=0 from edge features
  short8 aef;
  aef[0] = (short)f2bf(e0v.x); aef[1] = (short)f2bf(e0v.y);
  aef[2] = (short)f2bf(e0v.z); aef[3] = (short)f2bf(e0v.w);
  aef[4] = (short)f2bf(e1v.x); aef[5] = (short)f2bf(e1v.y);
  aef[6] = (short)f2bf(e1v.z); aef[7] = (short)f2bf(e1v.w);

  // ---- layer 1: H[128x128] = X @ W1 ; k-order {1,2,3,4,0} matches load order
  f32x4 acc[8];
  #pragma unroll
  for (int t = 0; t < 8; ++t) acc[t] = (f32x4)0.0f;

  #define L1STEP(AV, KS)                                                        \
    _Pragma("unroll")                                                           \
    for (int t = 0; t < 8; ++t) {                                               \
      const short8 b = *(const short8*)(W1 + ((KS) * 8 + t) * 512 + lane * 8);  \
      acc[t] = __builtin_amdgcn_mfma_f32_16x16x32_bf16(AV, b, acc[t], 0, 0, 0); \
    }
  L1STEP(g0, 1)
  L1STEP(g1, 2)
  L1STEP(g2, 3)
  L1STEP(g3, 4)
  L1STEP(aef, 0)
  #undef L1STEP

  // ---- relu + bias -> H A-frags, wave-private LDS (no barrier needed)
  #pragma unroll
  for (int t = 0; t < 8; ++t) {
    #pragma unroll
    for (int r = 0; r < 4; ++r) {
      float h = acc[t][r] + b1v[t];
      h = h > 0.0f ? h : 0.0f;
      const int k    = t * 16 + lr;
      const int frag = wid * 4 + (k >> 5);
      const int l2   = (((k >> 3) & 3) << 4) + lq * 4 + r;
      Hs[frag * 512 + l2 * 8 + (k & 7)] = f2bf(h);
    }
  }

  // ---- read back own H A-frags (same-wave RAW; compiler inserts lgkm wait)
  short8 a2[4];
  #pragma unroll
  for (int ks = 0; ks < 4; ++ks)
    a2[ks] = *(const short8*)(Hs + (wid * 4 + ks) * 512 + lane * 8);

  // ---- layer 2: OUT[128x64] = H @ W2 (B from global, L1/L2-hot)
  f32x4 acc2[4];
  #pragma unroll
  for (int t = 0; t < 4; ++t) acc2[t] = (f32x4)0.0f;
  #pragma unroll
  for (int t = 0; t < 4; ++t) {
    #pragma unroll
    for (int ks = 0; ks < 4; ++ks) {
      const short8 b = *(const short8*)(w2p + ((ks * 4 + t) * 64 + lane) * 8);
      acc2[t] = __builtin_amdgcn_mfma_f32_16x16x32_bf16(a2[ks], b, acc2[t], 0, 0, 0);
    }
  }

  // ---- epilogue: bias + f32 store
  const long mbase = (long)blockIdx.x * MT + wid * 16 + lq * 4;
  #pragma unroll
  for (int t = 0; t < 4; ++t) {
    #pragma unroll
    for (int r = 0; r < 4; ++r) {
      out[(mbase + r) * OD + t * 16 + lr] = acc2[t][r] + b2v[t];
    }
  }
}

extern "C" void kernel_launch(void* const* d_in, const int* in_sizes, int n_in,
                              void* d_out, int out_size, void* d_ws, size_t ws_size,
                              hipStream_t stream) {
  const int*   eidx = (const int*)d_in[0];      // (2, E) int32
  const float* nf   = (const float*)d_in[1];    // (NN, 64)
  const float* ef   = (const float*)d_in[2];    // (E, 32)
  const float* w1   = (const float*)d_in[3];    // (160, 128)
  const float* b1   = (const float*)d_in[4];    // (128,)
  const float* w2   = (const float*)d_in[5];    // (128, 64)
  const float* b2   = (const float*)d_in[6];    // (64,)
  float*       out  = (float*)d_out;            // (E, 64)

  unsigned short* nbf = (unsigned short*)d_ws;            // NN*ND
  unsigned short* w1p = nbf + (long)NN * ND;              // HD*IND
  unsigned short* w2p = w1p + (long)HD * IND;             // OD*HD

  cvt_nodes<<<1024, 256, 0, stream>>>(nf, nbf, (NN * ND) / 4);
  pack_w1<<<(HD * IND + 255) / 256, 256, 0, stream>>>(w1, w1p);
  pack_w2<<<(OD * HD + 255) / 256, 256, 0, stream>>>(w2, w2p);

  hipFuncSetAttribute((const void*)edge_mlp,
                      hipFuncAttributeMaxDynamicSharedMemorySize, SMEM_BYTES);
  edge_mlp<<<E_TOTAL / MT, NTHREADS, SMEM_BYTES, stream>>>(
      eidx, ef, nbf, w1p, w2p, b1, b2, out);
}